// Round 4
// baseline (360.691 us; speedup 1.0000x reference)
//
#include <hip/hip_runtime.h>
#include <math.h>

// I-BERT IntSoftmax, exact-numerics replication of the JAX reference.
// x: (1,12,2048,2048) f32; 24576 rows of S=2048.
// R4: pass-1 computes per-row max (monotone quant => row max of xi = xi(row max x))
//     and abs-max only; k_row is single-fused-loop with ONE barrier.

#define ROW_S 2048
#define RPB 8                    // rows per block in pass 1
#define P1_BLOCKS (24576 / RPB)  // 3072

typedef float floatx4 __attribute__((ext_vector_type(4)));

struct Scalars {
    double exp_sf_d;   // exp_sf (f64) — fixedpoint_mul divisor
    double inv_exp_sf; // RN(1/exp_sf_d) f64
    double m_int;      // 31-bit mantissa (f64)
    double inv_pow;    // 2^(e-31) exact
    float  sf;         // activation scale
    float  inv_sf;     // RN(1/sf)
    float  x0_int;     // floor(-0.6931/sf)
    float  inv_x0;     // RN(1/x0_int)
    float  b_int;      // floor(COEF1/sf)
    float  c_int;      // floor(COEF2/sf^2)
    float  thirty_x0;  // 30 * x0_int (exact)
    float  _pad;
};

// Markstein: with inv = RN(1/b), returns RN(a/b) bit-exactly.
__device__ __forceinline__ float div_rn(float a, float b, float inv) {
    const float q0 = __fmul_rn(a, inv);
    const float r  = __fmaf_rn(-b, q0, a);
    return __fmaf_rn(r, inv, q0);
}
__device__ __forceinline__ double ddiv_rn(double a, double b, double inv) {
    const double q0 = __dmul_rn(a, inv);
    const double r  = __fma_rn(-b, q0, a);
    return __fma_rn(r, inv, q0);
}

// Pass 1: per-row max of x + global abs-max partials. 8 rows/block, 32 lanes/row.
__global__ __launch_bounds__(256) void k_rowmax(const float* __restrict__ x,
                                                float* __restrict__ pabs,
                                                float* __restrict__ rowmax) {
    const int t   = threadIdx.x;
    const int rib = t >> 5;          // row in block, 0..7
    const int lir = t & 31;          // lane in row
    const size_t base4 = ((size_t)blockIdx.x * RPB + rib) * (ROW_S / 4) + lir;
    const float4* x4 = (const float4*)x;

    float vmax = -INFINITY, amax = 0.0f;
#pragma unroll
    for (int k = 0; k < 16; ++k) {
        float4 v = x4[base4 + (size_t)k * 32];
        vmax = fmaxf(vmax, fmaxf(fmaxf(v.x, v.y), fmaxf(v.z, v.w)));
        amax = fmaxf(amax, fmaxf(fmaxf(fabsf(v.x), fabsf(v.y)),
                                 fmaxf(fabsf(v.z), fabsf(v.w))));
    }
    // row max across the 32 lanes of this row (xor<32 stays in-group)
#pragma unroll
    for (int m = 16; m > 0; m >>= 1) vmax = fmaxf(vmax, __shfl_xor(vmax, m));
    if (lir == 0) rowmax[blockIdx.x * RPB + rib] = vmax;
    // abs max across full wave, then block
#pragma unroll
    for (int m = 32; m > 0; m >>= 1) amax = fmaxf(amax, __shfl_xor(amax, m));
    __shared__ float sa[4];
    if ((t & 63) == 0) sa[t >> 6] = amax;
    __syncthreads();
    if (t == 0) pabs[blockIdx.x] = fmaxf(fmaxf(sa[0], sa[1]), fmaxf(sa[2], sa[3]));
}

__global__ __launch_bounds__(256) void k_scalars(const float* __restrict__ pabs,
                                                 Scalars* __restrict__ sc) {
    const int tid = threadIdx.x;
    float amax = 0.0f;
    for (int i = tid; i < P1_BLOCKS; i += 256) amax = fmaxf(amax, pabs[i]);
#pragma unroll
    for (int m = 32; m > 0; m >>= 1) amax = fmaxf(amax, __shfl_xor(amax, m));
    __shared__ float sa[4];
    const int wave = tid >> 6, lane = tid & 63;
    if (lane == 0) sa[wave] = amax;
    __syncthreads();
    if (tid == 0) {
        const float sabs = fmaxf(fmaxf(sa[0], sa[1]), fmaxf(sa[2], sa[3]));
        // sym_scale: max(|min|,|max|) == max|x|; then clamp, /32767 (all f32 RN)
        const float sf    = __fdiv_rn(fmaxf(sabs, 1e-8f), 32767.0f);
        const float x0i   = floorf(__fdiv_rn((float)(-0.6931), sf));
        const float sfsq  = __fmul_rn(sf, sf);
        const float b_int = floorf(__fdiv_rn((float)(0.96963238 / 0.35815147), sf));
        const float c_int = floorf(__fdiv_rn((float)(1.0 / 0.35815147), sfsq));
        const float exp_sf = __fdiv_rn(__fmul_rn((float)(0.35815147), sfsq), 1073741824.0f);
        // global max of exp_int is exactly c_int * 2^30 (row-max element has
        // r=0,q=0 => z=c_int); min>=0, so sym_scale uses this max.
        const float emax   = __fmul_rn(c_int, 1073741824.0f);
        const float act_sf = __fdiv_rn(fmaxf(emax, 1e-8f), 32767.0f);
        // fixedpoint_mul scalar part (f64, per reference)
        const float  nsf = __fdiv_rn(exp_sf, act_sf);
        const double ns  = (double)nsf;
        int E;
        (void)frexp(ns, &E);                 // e = floor(log2(ns)) + 1 == E exactly
        const double m_int = rint(ldexp(ns, 31 - E));
        sc->exp_sf_d   = (double)exp_sf;
        sc->inv_exp_sf = 1.0 / (double)exp_sf;
        sc->m_int      = m_int;
        sc->inv_pow    = ldexp(1.0, E - 31);
        sc->sf         = sf;
        sc->inv_sf     = __fdiv_rn(1.0f, sf);
        sc->x0_int     = x0i;
        sc->inv_x0     = __fdiv_rn(1.0f, x0i);
        sc->b_int      = b_int;
        sc->c_int      = c_int;
        sc->thirty_x0  = __fmul_rn(30.0f, x0i);
    }
}

__global__ __launch_bounds__(256) void k_row(const float* __restrict__ x,
                                             float* __restrict__ out,
                                             const Scalars* __restrict__ scp,
                                             const float* __restrict__ rowmax) {
    const int tid = threadIdx.x;
    const size_t rowbase = (size_t)blockIdx.x * ROW_S;
    const float4* x4 = (const float4*)(x + rowbase);
    floatx4* o4 = (floatx4*)(out + rowbase);

    // issue global loads first; uniform scalar loads overlap
    const float4 va = x4[tid];
    const float4 vb = x4[tid + 256];
    const float  rm = rowmax[blockIdx.x];

    const Scalars sc = *scp;
    const float sf = sc.sf, inv_sf = sc.inv_sf;

    // ximax = xi(row max of x): every x->xi step is monotone non-decreasing,
    // so this is bit-identical to max over the row of xi.
    float ximax;
    {
        float t = rintf(div_rn(rm, sf, inv_sf));
        t = fminf(fmaxf(t, -32768.0f), 32767.0f);
        t = __fmul_rn(t, sf);
        ximax = div_rn(t, sf, inv_sf);
    }

    float xv[8] = {va.x, va.y, va.z, va.w, vb.x, vb.y, vb.z, vb.w};

    float e16[8];
    float ssum = 0.0f;
#pragma unroll
    for (int j = 0; j < 8; ++j) {
        // QuantAct(16): x_int = clip(rint(x/sf)); xi = (x_int*sf)/sf (all RN, no FMA)
        float t = rintf(div_rn(xv[j], sf, inv_sf));
        t = fminf(fmaxf(t, -32768.0f), 32767.0f);
        t = __fmul_rn(t, sf);
        t = div_rn(t, sf, inv_sf);
        // int_exp
        const float xs = __fsub_rn(t, ximax);
        const float xm = fmaxf(xs, sc.thirty_x0);
        const float qf = floorf(div_rn(xm, sc.x0_int, sc.inv_x0));
        const float r  = __fsub_rn(xm, __fmul_rn(sc.x0_int, qf));
        // z = r*(r+b)+c — must NOT contract to FMA (XLA CPU doesn't)
        const float z  = __fadd_rn(__fmul_rn(r, __fadd_rn(r, sc.b_int)), sc.c_int);
        const int   qi = (int)qf;                          // qf in [0,30]
        const float p2 = __int_as_float((157 - qi) << 23); // exactly 2^(30-qi)
        const float ei = fmaxf(floorf(__fmul_rn(z, p2)), 0.0f);
        // fixedpoint_mul in f64 (reference runs in double)
        const double a  = (double)ei;
        const double zi = rint(ddiv_rn(a, sc.exp_sf_d, sc.inv_exp_sf));
        double ov = rint(__dmul_rn(__dmul_rn(zi, sc.m_int), sc.inv_pow));
        ov = fmin(fmax(ov, -32768.0), 32767.0);
        const float v = (float)ov;   // integer-valued, exact
        e16[j] = v;
        ssum += v;   // non-negative ints, row sum < 2^24 -> order-free exact
    }

    // block sum: wave butterfly + 4-slot LDS, single barrier
    __shared__ float red[4];
    const int wave = tid >> 6, lane = tid & 63;
#pragma unroll
    for (int m = 32; m > 0; m >>= 1) ssum += __shfl_xor(ssum, m);
    if (lane == 0) red[wave] = ssum;
    __syncthreads();
    const float s = ((red[0] + red[1]) + (red[2] + red[3]));
    const float factor = floorf(__fdiv_rn(4294967296.0f, s));

    float ov[8];
#pragma unroll
    for (int j = 0; j < 8; ++j) {
        // /2^24 == *2^-24 exactly, then *2^-8 exact
        const float oi = floorf(__fmul_rn(__fmul_rn(e16[j], factor), 5.9604644775390625e-8f));
        ov[j] = __fmul_rn(oi, 0.00390625f);
    }
    floatx4 w0 = {ov[0], ov[1], ov[2], ov[3]};
    floatx4 w1 = {ov[4], ov[5], ov[6], ov[7]};
    __builtin_nontemporal_store(w0, &o4[tid]);
    __builtin_nontemporal_store(w1, &o4[tid + 256]);
}

extern "C" void kernel_launch(void* const* d_in, const int* in_sizes, int n_in,
                              void* d_out, int out_size, void* d_ws, size_t ws_size,
                              hipStream_t stream) {
    const float* x = (const float*)d_in[0];
    float* out = (float*)d_out;
    const int n = in_sizes[0];          // 50331648
    const int rows = n / ROW_S;         // 24576

    Scalars* sc   = (Scalars*)d_ws;
    float* pabs   = (float*)((char*)d_ws + 256);
    float* rowmax = (float*)((char*)d_ws + 32768);

    k_rowmax<<<P1_BLOCKS, 256, 0, stream>>>(x, pabs, rowmax);
    k_scalars<<<1, 256, 0, stream>>>(pabs, sc);
    k_row<<<rows, 256, 0, stream>>>(x, out, sc, rowmax);
}